// Round 1
// baseline (97.283 us; speedup 1.0000x reference)
//
#include <hip/hip_runtime.h>
#include <math.h>

#define B 16
#define F 8
#define C 256
#define HW 1024
#define NROWS (B*F*C)       // 32768
#define KC 205              // ceil(0.8*256)

// ---------------------------------------------------------------------------
// K1: per-(b,f,c) row stats over the 1024-element h*w plane.
// One wave (64 lanes) per row; 4 float4 loads per lane; shfl reduce.
// ---------------------------------------------------------------------------
__global__ __launch_bounds__(256) void k_rowstat(const float* __restrict__ x,
                                                 float* __restrict__ sums,
                                                 float* __restrict__ maxs) {
    const int wave = threadIdx.x >> 6;
    const int lane = threadIdx.x & 63;
    const int row  = blockIdx.x * 4 + wave;
    const float* p = x + (size_t)row * HW;

    float s = 0.f, m = -INFINITY;
#pragma unroll
    for (int k = 0; k < 4; ++k) {
        float4 v = *reinterpret_cast<const float4*>(p + k * 256 + lane * 4);
        s += (v.x + v.y) + (v.z + v.w);
        m = fmaxf(m, fmaxf(fmaxf(v.x, v.y), fmaxf(v.z, v.w)));
    }
#pragma unroll
    for (int off = 32; off > 0; off >>= 1) {
        s += __shfl_down(s, off);
        m = fmaxf(m, __shfl_down(m, off));
    }
    if (lane == 0) { sums[row] = s; maxs[row] = m; }
}

// ---------------------------------------------------------------------------
// K2a: TimeAttention. 1 block, 128 threads (one per (b,f)).
// t_avg/t_max from row stats, 8x8 MLP x2, sigmoid.
// WTA(ratio=0.9, n=8): k = ceil(7.2) = 8 -> thr = row min -> mask_t == 1,
// so sal_t = ta exactly.
// ---------------------------------------------------------------------------
__global__ __launch_bounds__(128) void k_time_att(const float* __restrict__ sums,
                                                  const float* __restrict__ maxs,
                                                  const float* __restrict__ w1,
                                                  const float* __restrict__ w2,
                                                  float* __restrict__ ta_out) {
    __shared__ float avg[B * F], mx[B * F], hsum[B * F];
    const int t = threadIdx.x;          // b*8 + f
    float s = 0.f, m = -INFINITY;
    const float* sp = sums + t * C;
    const float* mp = maxs + t * C;
    for (int c = 0; c < C; ++c) { s += sp[c]; m = fmaxf(m, mp[c]); }
    avg[t] = s * (1.f / (float)(C * HW));
    mx[t]  = m;
    __syncthreads();

    const int b = t >> 3, h = t & 7;
    float ha = 0.f, hm = 0.f;
    for (int n = 0; n < F; ++n) {
        float w = w1[h * F + n];
        ha += w * avg[b * F + n];
        hm += w * mx[b * F + n];
    }
    hsum[t] = fmaxf(ha, 0.f) + fmaxf(hm, 0.f);
    __syncthreads();

    // t's role now: output index n = h
    float o = 0.f;
    for (int hh = 0; hh < F; ++hh) o += w2[h * F + hh] * hsum[b * F + hh];
    ta_out[t] = 1.f / (1.f + expf(-o));
}

// ---------------------------------------------------------------------------
// K2b: ChannelAttention + WTA + combined per-row scale.
// 16 blocks (one per b) x 256 threads (one per channel / hidden unit).
// c_avg[b,c] = sum_f ta*sum_hw / 8192 ; c_max[b,c] = max_f ta*max_hw (ta>0).
// WTA: mask_i = (#{j : ca_j > ca_i} < 205)  ==  ca_i >= 205th-largest.
// srow[b,f,c] = ta[b,f] * (ca*mask)[b,c]   (mask^2 == mask).
// ---------------------------------------------------------------------------
__global__ __launch_bounds__(256) void k_chan_att(const float* __restrict__ sums,
                                                  const float* __restrict__ maxs,
                                                  const float* __restrict__ ta,
                                                  const float* __restrict__ w1,
                                                  const float* __restrict__ w2,
                                                  float* __restrict__ srow) {
    __shared__ float vavg[C], vmax[C], hsum[C], ca[C];
    const int b = blockIdx.x;
    const int t = threadIdx.x;

    float s = 0.f, m = -INFINITY;
    for (int f = 0; f < F; ++f) {
        float w = ta[b * F + f];
        s += w * sums[(b * F + f) * C + t];
        m = fmaxf(m, w * maxs[(b * F + f) * C + t]);
    }
    vavg[t] = s * (1.f / (float)(F * HW));
    vmax[t] = m;
    __syncthreads();

    float ha = 0.f, hm = 0.f;
    const float* w1r = w1 + t * C;
    for (int n = 0; n < C; ++n) {
        float w = w1r[n];
        ha += w * vavg[n];
        hm += w * vmax[n];
    }
    hsum[t] = fmaxf(ha, 0.f) + fmaxf(hm, 0.f);
    __syncthreads();

    float o = 0.f;
    const float* w2r = w2 + t * C;
    for (int h = 0; h < C; ++h) o += w2r[h] * hsum[h];
    float cav = 1.f / (1.f + expf(-o));
    ca[t] = cav;
    __syncthreads();

    int cnt = 0;
    for (int j = 0; j < C; ++j) cnt += (ca[j] > cav);
    float sc = (cnt < KC) ? cav : 0.f;

    for (int f = 0; f < F; ++f)
        srow[b * (F * C) + f * C + t] = ta[b * F + f] * sc;
}

// ---------------------------------------------------------------------------
// K3: out = x * srow[row], row = flat_idx / 1024. float4 grid-stride.
// ---------------------------------------------------------------------------
__global__ __launch_bounds__(256) void k_scale(const float* __restrict__ x,
                                               const float* __restrict__ srow,
                                               float* __restrict__ out,
                                               int n4) {
    int idx = blockIdx.x * blockDim.x + threadIdx.x;
    const int stride = gridDim.x * blockDim.x;
    for (int i = idx; i < n4; i += stride) {
        float4 v = reinterpret_cast<const float4*>(x)[i];
        float sc = srow[i >> 8];           // (i*4)/1024
        v.x *= sc; v.y *= sc; v.z *= sc; v.w *= sc;
        reinterpret_cast<float4*>(out)[i] = v;
    }
}

extern "C" void kernel_launch(void* const* d_in, const int* in_sizes, int n_in,
                              void* d_out, int out_size, void* d_ws, size_t ws_size,
                              hipStream_t stream) {
    const float* x     = (const float*)d_in[0];
    const float* ta_w1 = (const float*)d_in[1];
    const float* ta_w2 = (const float*)d_in[2];
    const float* ca_w1 = (const float*)d_in[3];
    const float* ca_w2 = (const float*)d_in[4];
    float* out = (float*)d_out;

    float* ws   = (float*)d_ws;
    float* sums = ws;                    // [32768]
    float* maxs = ws + NROWS;            // [32768]
    float* ta   = ws + 2 * NROWS;        // [128]
    float* srow = ws + 2 * NROWS + 128;  // [32768]

    k_rowstat<<<NROWS / 4, 256, 0, stream>>>(x, sums, maxs);
    k_time_att<<<1, 128, 0, stream>>>(sums, maxs, ta_w1, ta_w2, ta);
    k_chan_att<<<B, 256, 0, stream>>>(sums, maxs, ta, ca_w1, ca_w2, srow);
    k_scale<<<2048, 256, 0, stream>>>(x, srow, out, NROWS * HW / 4);
}

// Round 2
// 88.791 us; speedup vs baseline: 1.0956x; 1.0956x over previous
//
#include <hip/hip_runtime.h>
#include <math.h>

#define B 16
#define F 8
#define C 256
#define HW 1024
#define NROWS (B*F*C)       // 32768
#define KC 205              // ceil(0.8*256)

typedef float f4 __attribute__((ext_vector_type(4)));

// ---------------------------------------------------------------------------
// K1: per-(b,f,c) row stats over the 1024-element h*w plane.
// One wave (64 lanes) per row; 4 float4 loads per lane; shfl reduce.
// Normal (cached) loads: we WANT x resident in L3 for k_scale's re-read.
// ---------------------------------------------------------------------------
__global__ __launch_bounds__(256) void k_rowstat(const float* __restrict__ x,
                                                 float* __restrict__ sums,
                                                 float* __restrict__ maxs) {
    const int wave = threadIdx.x >> 6;
    const int lane = threadIdx.x & 63;
    const int row  = blockIdx.x * 4 + wave;
    const float* p = x + (size_t)row * HW;

    float s = 0.f, m = -INFINITY;
#pragma unroll
    for (int k = 0; k < 4; ++k) {
        float4 v = *reinterpret_cast<const float4*>(p + k * 256 + lane * 4);
        s += (v.x + v.y) + (v.z + v.w);
        m = fmaxf(m, fmaxf(fmaxf(v.x, v.y), fmaxf(v.z, v.w)));
    }
#pragma unroll
    for (int off = 32; off > 0; off >>= 1) {
        s += __shfl_down(s, off);
        m = fmaxf(m, __shfl_down(m, off));
    }
    if (lane == 0) { sums[row] = s; maxs[row] = m; }
}

// ---------------------------------------------------------------------------
// K2: pool row stats over c -> per-(b,f) sum/max. 32 blocks x 4 waves;
// one wave per (b,f); coalesced loads + shfl reduce.
// ---------------------------------------------------------------------------
__global__ __launch_bounds__(256) void k_tpool(const float* __restrict__ sums,
                                               const float* __restrict__ maxs,
                                               float* __restrict__ tsum,
                                               float* __restrict__ tmax) {
    const int wave = threadIdx.x >> 6;
    const int lane = threadIdx.x & 63;
    const int bf   = blockIdx.x * 4 + wave;     // 0..127
    const float* sp = sums + bf * C;
    const float* mp = maxs + bf * C;
    float s = (sp[lane] + sp[lane + 64]) + (sp[lane + 128] + sp[lane + 192]);
    float m = fmaxf(fmaxf(mp[lane], mp[lane + 64]),
                    fmaxf(mp[lane + 128], mp[lane + 192]));
#pragma unroll
    for (int off = 32; off > 0; off >>= 1) {
        s += __shfl_down(s, off);
        m = fmaxf(m, __shfl_down(m, off));
    }
    if (lane == 0) { tsum[bf] = s; tmax[bf] = m; }
}

// ---------------------------------------------------------------------------
// K3: ChannelAttention (+ the tiny 8x8 time-MLP computed redundantly per
// block from the 128-element pooled arrays) + WTA + combined per-row scale.
// 16 blocks (one per b) x 256 threads.
// WTA(time): k = ceil(0.9*8) = 8 -> mask_t == 1, sal_t = ta exactly.
// c_avg[b,c] = sum_f ta*sum_hw / 8192 ; c_max[b,c] = max_f ta*max_hw (ta>0).
// WTA(chan): mask_i = (#{j : ca_j > ca_i} < 205)  ==  ca_i >= 205th-largest.
// srow[b,f,c] = ta[b,f] * (ca*mask)[b,c]   (mask^2 == mask).
// ---------------------------------------------------------------------------
__global__ __launch_bounds__(256) void k_chan_att(const float* __restrict__ sums,
                                                  const float* __restrict__ maxs,
                                                  const float* __restrict__ tsum,
                                                  const float* __restrict__ tmax,
                                                  const float* __restrict__ tw1,
                                                  const float* __restrict__ tw2,
                                                  const float* __restrict__ w1,
                                                  const float* __restrict__ w2,
                                                  float* __restrict__ srow) {
    __shared__ float tav[B * F], tmx[B * F], th[B * F], ta[B * F];
    __shared__ float vavg[C], vmax[C], hsum[C], ca[C];
    const int b = blockIdx.x;
    const int t = threadIdx.x;

    // --- time MLP (redundant per block; 128 values, trivial) ---
    if (t < B * F) {
        tav[t] = tsum[t] * (1.f / (float)(C * HW));
        tmx[t] = tmax[t];
    }
    __syncthreads();
    if (t < B * F) {
        const int bb = t >> 3, h = t & 7;
        float ha = 0.f, hm = 0.f;
        for (int n = 0; n < F; ++n) {
            float w = tw1[h * F + n];
            ha += w * tav[bb * F + n];
            hm += w * tmx[bb * F + n];
        }
        th[t] = fmaxf(ha, 0.f) + fmaxf(hm, 0.f);
    }
    __syncthreads();
    if (t < B * F) {
        const int bb = t >> 3, h = t & 7;
        float o = 0.f;
        for (int hh = 0; hh < F; ++hh) o += tw2[h * F + hh] * th[bb * F + hh];
        ta[t] = 1.f / (1.f + expf(-o));
    }
    __syncthreads();

    // --- channel pooling of ta-scaled x via row stats ---
    float s = 0.f, m = -INFINITY;
    for (int f = 0; f < F; ++f) {
        float w = ta[b * F + f];
        s += w * sums[(b * F + f) * C + t];
        m = fmaxf(m, w * maxs[(b * F + f) * C + t]);
    }
    vavg[t] = s * (1.f / (float)(F * HW));
    vmax[t] = m;
    __syncthreads();

    // --- channel MLP ---
    float ha = 0.f, hm = 0.f;
    const float* w1r = w1 + t * C;
    for (int n = 0; n < C; ++n) {
        float w = w1r[n];
        ha += w * vavg[n];
        hm += w * vmax[n];
    }
    hsum[t] = fmaxf(ha, 0.f) + fmaxf(hm, 0.f);
    __syncthreads();

    float o = 0.f;
    const float* w2r = w2 + t * C;
    for (int h = 0; h < C; ++h) o += w2r[h] * hsum[h];
    float cav = 1.f / (1.f + expf(-o));
    ca[t] = cav;
    __syncthreads();

    // --- WTA + combined scale ---
    int cnt = 0;
    for (int j = 0; j < C; ++j) cnt += (ca[j] > cav);
    float sc = (cnt < KC) ? cav : 0.f;

    for (int f = 0; f < F; ++f)
        srow[b * (F * C) + f * C + t] = ta[b * F + f] * sc;
}

// ---------------------------------------------------------------------------
// K4: out = x * srow[row], row = flat_idx / 1024. float4 grid-stride.
// x loads cached (L3-resident from K1); out stores non-temporal so the
// 128 MiB output doesn't evict x from the 256 MiB L3.
// ---------------------------------------------------------------------------
__global__ __launch_bounds__(256) void k_scale(const float* __restrict__ x,
                                               const float* __restrict__ srow,
                                               float* __restrict__ out,
                                               int n4) {
    int idx = blockIdx.x * blockDim.x + threadIdx.x;
    const int stride = gridDim.x * blockDim.x;
    for (int i = idx; i < n4; i += stride) {
        f4 v = reinterpret_cast<const f4*>(x)[i];
        float sc = srow[i >> 8];           // (i*4)/1024
        v *= sc;
        __builtin_nontemporal_store(v, reinterpret_cast<f4*>(out) + i);
    }
}

extern "C" void kernel_launch(void* const* d_in, const int* in_sizes, int n_in,
                              void* d_out, int out_size, void* d_ws, size_t ws_size,
                              hipStream_t stream) {
    const float* x     = (const float*)d_in[0];
    const float* ta_w1 = (const float*)d_in[1];
    const float* ta_w2 = (const float*)d_in[2];
    const float* ca_w1 = (const float*)d_in[3];
    const float* ca_w2 = (const float*)d_in[4];
    float* out = (float*)d_out;

    float* ws   = (float*)d_ws;
    float* sums = ws;                    // [32768]
    float* maxs = ws + NROWS;            // [32768]
    float* tsum = ws + 2 * NROWS;        // [128]
    float* tmax = ws + 2 * NROWS + 128;  // [128]
    float* srow = ws + 2 * NROWS + 256;  // [32768]

    k_rowstat<<<NROWS / 4, 256, 0, stream>>>(x, sums, maxs);
    k_tpool<<<32, 256, 0, stream>>>(sums, maxs, tsum, tmax);
    k_chan_att<<<B, 256, 0, stream>>>(sums, maxs, tsum, tmax,
                                      ta_w1, ta_w2, ca_w1, ca_w2, srow);
    k_scale<<<2048, 256, 0, stream>>>(x, srow, out, NROWS * HW / 4);
}

// Round 5
// 86.453 us; speedup vs baseline: 1.1253x; 1.0271x over previous
//
#include <hip/hip_runtime.h>
#include <math.h>

#define B 16
#define F 8
#define C 256
#define HW 1024
#define NROWS (B*F*C)       // 32768
#define KC 205              // ceil(0.8*256)

typedef float f4 __attribute__((ext_vector_type(4)));

// ---------------------------------------------------------------------------
// K1: per-(b,f,c) row stats over the 1024-element h*w plane.
// One wave (64 lanes) per row; 4 float4 loads per lane; shfl reduce.
// Normal (cached) loads: we WANT x resident in L3 for k_scale's re-read.
// ---------------------------------------------------------------------------
__global__ __launch_bounds__(256) void k_rowstat(const float* __restrict__ x,
                                                 float* __restrict__ sums,
                                                 float* __restrict__ maxs) {
    const int wave = threadIdx.x >> 6;
    const int lane = threadIdx.x & 63;
    const int row  = blockIdx.x * 4 + wave;
    const float* p = x + (size_t)row * HW;

    float s = 0.f, m = -INFINITY;
#pragma unroll
    for (int k = 0; k < 4; ++k) {
        float4 v = *reinterpret_cast<const float4*>(p + k * 256 + lane * 4);
        s += (v.x + v.y) + (v.z + v.w);
        m = fmaxf(m, fmaxf(fmaxf(v.x, v.y), fmaxf(v.z, v.w)));
    }
#pragma unroll
    for (int off = 32; off > 0; off >>= 1) {
        s += __shfl_down(s, off);
        m = fmaxf(m, __shfl_down(m, off));
    }
    if (lane == 0) { sums[row] = s; maxs[row] = m; }
}

// ---------------------------------------------------------------------------
// K2: full attention chain, one block per batch. 16 blocks x 256 threads.
//   tpool (wave-per-f over c) -> 8x8 time MLP -> ta[f]
//     (WTA time: k=ceil(0.9*8)=8 -> thr = min -> mask_t==1 -> sal_t = ta)
//   chan pool: c_avg = sum_f ta*sum/8192 ; c_max = max_f ta*max  (ta>0)
//   256x256 MLP x2 -> ca ; WTA: keep iff #{j: ca_j > ca_i} < 205
//   srow[b,f,c] = ta[f] * ca * mask        (mask^2 == mask)
// ---------------------------------------------------------------------------
__global__ __launch_bounds__(256) void k_att(const float* __restrict__ sums,
                                             const float* __restrict__ maxs,
                                             const float* __restrict__ tw1,
                                             const float* __restrict__ tw2,
                                             const float* __restrict__ w1,
                                             const float* __restrict__ w2,
                                             float* __restrict__ srow) {
    __shared__ float tavg[F], tmx[F], th[F], ta_s[F];
    __shared__ float vavg[C], vmax[C], hsum[C], ca[C];
    const int b    = blockIdx.x;
    const int t    = threadIdx.x;
    const int wave = t >> 6;
    const int lane = t & 63;

    // tpool: wave w reduces f = w and f = w+4
    for (int f = wave; f < F; f += 4) {
        const float* sp = sums + (b * F + f) * C;
        const float* mp = maxs + (b * F + f) * C;
        float s = (sp[lane] + sp[lane + 64]) + (sp[lane + 128] + sp[lane + 192]);
        float m = fmaxf(fmaxf(mp[lane], mp[lane + 64]),
                        fmaxf(mp[lane + 128], mp[lane + 192]));
#pragma unroll
        for (int off = 32; off > 0; off >>= 1) {
            s += __shfl_down(s, off);
            m = fmaxf(m, __shfl_down(m, off));
        }
        if (lane == 0) { tavg[f] = s * (1.f / (float)(C * HW)); tmx[f] = m; }
    }
    __syncthreads();

    // time MLP (8x8), threads 0..7
    if (t < F) {
        float ha = 0.f, hm = 0.f;
        for (int n = 0; n < F; ++n) {
            float w = tw1[t * F + n];
            ha += w * tavg[n];
            hm += w * tmx[n];
        }
        th[t] = fmaxf(ha, 0.f) + fmaxf(hm, 0.f);
    }
    __syncthreads();
    if (t < F) {
        float o = 0.f;
        for (int h = 0; h < F; ++h) o += tw2[t * F + h] * th[h];
        ta_s[t] = 1.f / (1.f + expf(-o));
    }
    __syncthreads();

    // channel pooling of ta-scaled x via row stats (t = c)
    {
        float s = 0.f, m = -INFINITY;
        for (int f = 0; f < F; ++f) {
            float w = ta_s[f];
            s += w * sums[(b * F + f) * C + t];
            m = fmaxf(m, w * maxs[(b * F + f) * C + t]);
        }
        vavg[t] = s * (1.f / (float)(F * HW));
        vmax[t] = m;
    }
    __syncthreads();

    // channel MLP layer 1 (t = hidden)
    {
        float ha = 0.f, hm = 0.f;
        const float* w1r = w1 + t * C;
        for (int n = 0; n < C; ++n) {
            float w = w1r[n];
            ha += w * vavg[n];
            hm += w * vmax[n];
        }
        hsum[t] = fmaxf(ha, 0.f) + fmaxf(hm, 0.f);
    }
    __syncthreads();

    // layer 2 + sigmoid (t = out channel)
    float cav;
    {
        float o = 0.f;
        const float* w2r = w2 + t * C;
        for (int h = 0; h < C; ++h) o += w2r[h] * hsum[h];
        cav = 1.f / (1.f + expf(-o));
        ca[t] = cav;
    }
    __syncthreads();

    // WTA + combined per-row scale
    int rank = 0;
    for (int j = 0; j < C; ++j) rank += (ca[j] > cav);
    float sc = (rank < KC) ? cav : 0.f;
    for (int f = 0; f < F; ++f)
        srow[b * (F * C) + f * C + t] = ta_s[f] * sc;
}

// ---------------------------------------------------------------------------
// K3: out = x * srow[row], row = f4_idx >> 8. float4 grid-stride.
// x loads cached (L3-resident from K1); out stores non-temporal so the
// 128 MiB output doesn't evict x from the 256 MiB L3.
// ---------------------------------------------------------------------------
__global__ __launch_bounds__(256) void k_scale(const float* __restrict__ x,
                                               const float* __restrict__ srow,
                                               float* __restrict__ out,
                                               int n4) {
    int idx = blockIdx.x * blockDim.x + threadIdx.x;
    const int stride = gridDim.x * blockDim.x;
    for (int i = idx; i < n4; i += stride) {
        f4 v = reinterpret_cast<const f4*>(x)[i];
        float sc = srow[i >> 8];
        v *= sc;
        __builtin_nontemporal_store(v, reinterpret_cast<f4*>(out) + i);
    }
}

extern "C" void kernel_launch(void* const* d_in, const int* in_sizes, int n_in,
                              void* d_out, int out_size, void* d_ws, size_t ws_size,
                              hipStream_t stream) {
    const float* x     = (const float*)d_in[0];
    const float* ta_w1 = (const float*)d_in[1];
    const float* ta_w2 = (const float*)d_in[2];
    const float* ca_w1 = (const float*)d_in[3];
    const float* ca_w2 = (const float*)d_in[4];
    float* out = (float*)d_out;

    float* ws   = (float*)d_ws;
    float* sums = ws;                    // [32768]
    float* maxs = ws + NROWS;            // [32768]
    float* srow = ws + 2 * NROWS;        // [32768]

    k_rowstat<<<NROWS / 4, 256, 0, stream>>>(x, sums, maxs);
    k_att<<<B, 256, 0, stream>>>(sums, maxs, ta_w1, ta_w2, ca_w1, ca_w2, srow);
    k_scale<<<2048, 256, 0, stream>>>(x, srow, out, NROWS * HW / 4);
}